// Round 1
// baseline (1957.073 us; speedup 1.0000x reference)
//
#include <hip/hip_runtime.h>
#include <cmath>

#define NNODES 50000
#define NEDGES 800000
#define ORIG_FEA 92
#define NBR_FEA 41
#define HID 64
#define BN_EPS 1e-5f

// ---------------------------------------------------------------------------
// Fold embedding2 into per-layer edge weights:
//   Wcf[i] = W2 @ Wf[i][128:192,:]   (41x64), bcf[i] = bf[i] + b2 @ Wf[i][128:192,:]
//   Wcs[i] = W2 @ Ws[i][128:192,:]   (41x64), bcs[i] = bs[i] + b2 @ Ws[i][128:192,:]
// grid = 6 blocks: (layer, f/s)
// ---------------------------------------------------------------------------
__global__ void combine_weights(const float* __restrict__ W2, const float* __restrict__ b2,
                                const float* __restrict__ Wf, const float* __restrict__ bf,
                                const float* __restrict__ Ws, const float* __restrict__ bs,
                                float* __restrict__ Wcf, float* __restrict__ Wcs,
                                float* __restrict__ bcf, float* __restrict__ bcs) {
    int layer = blockIdx.x >> 1;
    int is_s = blockIdx.x & 1;
    const float* Wbig = (is_s ? Ws : Wf) + layer * 192 * HID + 128 * HID; // [64,64] e-part
    const float* bvec = (is_s ? bs : bf) + layer * HID;
    float* Wc = (is_s ? Wcs : Wcf) + layer * NBR_FEA * HID;
    float* bc = (is_s ? bcs : bcf) + layer * HID;

    for (int idx = threadIdx.x; idx < NBR_FEA * HID; idx += blockDim.x) {
        int r = idx / HID, c = idx % HID;
        float acc = 0.f;
        for (int k = 0; k < HID; ++k) acc += W2[r * HID + k] * Wbig[k * HID + c];
        Wc[idx] = acc;
    }
    for (int c = threadIdx.x; c < HID; c += blockDim.x) {
        float acc = bvec[c];
        for (int k = 0; k < HID; ++k) acc += b2[k] * Wbig[k * HID + c];
        bc[c] = acc;
    }
}

// ---------------------------------------------------------------------------
// h = x @ W1 + b1 : one wave per node, lane = output channel
// ---------------------------------------------------------------------------
__global__ void embed_nodes(const float* __restrict__ x, const float* __restrict__ W1,
                            const float* __restrict__ b1, float* __restrict__ h) {
    int lane = threadIdx.x & 63;
    int wid = (blockIdx.x * blockDim.x + threadIdx.x) >> 6;
    int nw = (gridDim.x * blockDim.x) >> 6;
    for (int n = wid; n < NNODES; n += nw) {
        float acc = b1[lane];
        const float* xr = x + (long)n * ORIG_FEA;
        for (int k = 0; k < ORIG_FEA; ++k) acc = fmaf(xr[k], W1[k * HID + lane], acc);
        h[n * HID + lane] = acc;
    }
}

// ---------------------------------------------------------------------------
// Node projections for layer i:
//   Ttgt[n][0:64]   = h@Wf[0:64]   + bcf    Ttgt[n][64:128] = h@Ws[0:64]   + bcs
//   Tsrc[n][0:64]   = h@Wf[64:128]          Tsrc[n][64:128] = h@Ws[64:128]
// block: 256 threads, p = tid>>6 selects which of the 4 projections.
// ---------------------------------------------------------------------------
__global__ void node_proj(const float* __restrict__ h,
                          const float* __restrict__ Wf, const float* __restrict__ Ws,
                          const float* __restrict__ bcf, const float* __restrict__ bcs,
                          float* __restrict__ Ttgt, float* __restrict__ Tsrc, int layer) {
    __shared__ float Wl[4][HID][HID]; // 64 KB
    int p = threadIdx.x >> 6;
    int c = threadIdx.x & 63;
    const float* Wsrc = ((p == 0) || (p == 2)) ? Wf : Ws;
    int row0 = (p < 2) ? 0 : 64;
    const float* Wbase = Wsrc + layer * 192 * HID + row0 * HID;
    for (int k = 0; k < HID; ++k) Wl[p][k][c] = Wbase[k * HID + c];
    float bias = (p == 0) ? bcf[layer * HID + c] : ((p == 1) ? bcs[layer * HID + c] : 0.f);
    __syncthreads();

    for (int n = blockIdx.x; n < NNODES; n += gridDim.x) {
        const float* hr = h + n * HID;
        float acc = bias;
        #pragma unroll 8
        for (int k = 0; k < HID; ++k) acc = fmaf(hr[k], Wl[p][k][c], acc);
        float* dst = (p == 0) ? (Ttgt + n * 128 + c)
                   : (p == 1) ? (Ttgt + n * 128 + 64 + c)
                   : (p == 2) ? (Tsrc + n * 128 + c)
                              : (Tsrc + n * 128 + 64 + c);
        *dst = acc;
    }
}

// ---------------------------------------------------------------------------
// Edge kernel: one wave per edge (grid-stride). lane = channel.
//   pre_f = Ttgt[tgt][0:64] + Tsrc[src][0:64] + ea@Wcf   (bias already in Ttgt)
//   pre_s = Ttgt[tgt][64:]  + Tsrc[src][64:]  + ea@Wcs
//   msg = sigmoid(pre_f) * softplus(pre_s);  atomicAdd into agg[tgt]
// Weights held in registers (82 VGPRs), ea broadcast via readlane.
// ---------------------------------------------------------------------------
__global__ void edge_kernel(const float* __restrict__ ea, const int* __restrict__ eidx,
                            const float* __restrict__ Ttgt, const float* __restrict__ Tsrc,
                            const float* __restrict__ Wcf, const float* __restrict__ Wcs,
                            float* __restrict__ agg) {
    int lane = threadIdx.x & 63;
    int wid = (blockIdx.x * blockDim.x + threadIdx.x) >> 6;
    int nw = (gridDim.x * blockDim.x) >> 6;

    float wf[NBR_FEA], ws[NBR_FEA];
    #pragma unroll
    for (int k = 0; k < NBR_FEA; ++k) {
        wf[k] = Wcf[k * HID + lane];
        ws[k] = Wcs[k * HID + lane];
    }

    for (int e = wid; e < NEDGES; e += nw) {
        int src = eidx[e];
        int tgt = eidx[NEDGES + e];
        float eav = (lane < NBR_FEA) ? ea[(long)e * NBR_FEA + lane] : 0.f;
        float accf = Ttgt[tgt * 128 + lane] + Tsrc[src * 128 + lane];
        float accs = Ttgt[tgt * 128 + 64 + lane] + Tsrc[src * 128 + 64 + lane];
        #pragma unroll
        for (int k = 0; k < NBR_FEA; ++k) {
            float a = __uint_as_float(__builtin_amdgcn_readlane(__float_as_uint(eav), k));
            accf = fmaf(a, wf[k], accf);
            accs = fmaf(a, ws[k], accs);
        }
        float gate = 1.f / (1.f + __expf(-accf));
        float sp = fmaxf(accs, 0.f) + log1pf(__expf(-fabsf(accs)));
        atomicAdd(&agg[tgt * HID + lane], gate * sp);
    }
}

// ---------------------------------------------------------------------------
// BN stats: sum and sumsq per channel of (h + agg). stats pre-zeroed.
// ---------------------------------------------------------------------------
__global__ void bn_stats(const float* __restrict__ h, const float* __restrict__ agg,
                         float* __restrict__ stats) {
    int lane = threadIdx.x & 63;
    int w = threadIdx.x >> 6;
    int gw = (blockIdx.x * blockDim.x + threadIdx.x) >> 6;
    int nw = (gridDim.x * blockDim.x) >> 6;
    float s = 0.f, sq = 0.f;
    for (int n = gw; n < NNODES; n += nw) {
        float v = h[n * HID + lane] + agg[n * HID + lane];
        s += v;
        sq = fmaf(v, v, sq);
    }
    __shared__ float ls[4][64], lq[4][64];
    ls[w][lane] = s; lq[w][lane] = sq;
    __syncthreads();
    if (threadIdx.x < 64) {
        float ts = ls[0][lane] + ls[1][lane] + ls[2][lane] + ls[3][lane];
        float tq = lq[0][lane] + lq[1][lane] + lq[2][lane] + lq[3][lane];
        atomicAdd(&stats[lane], ts);
        atomicAdd(&stats[64 + lane], tq);
    }
}

// ---------------------------------------------------------------------------
// BN apply (+ optional ReLU), in place into h:  h = BN(h + agg)
// ---------------------------------------------------------------------------
__global__ void bn_apply(float* __restrict__ h, const float* __restrict__ agg,
                         const float* __restrict__ stats, const float* __restrict__ gamma,
                         const float* __restrict__ beta, int relu) {
    const float invn = 1.f / (float)NNODES;
    long total = (long)NNODES * HID;
    for (long i = blockIdx.x * blockDim.x + threadIdx.x; i < total;
         i += (long)gridDim.x * blockDim.x) {
        int c = (int)(i & 63);
        float mean = stats[c] * invn;
        float var = stats[64 + c] * invn - mean * mean;
        float rs = rsqrtf(var + BN_EPS);
        float v = h[i] + agg[i];
        float y = (v - mean) * rs * gamma[c] + beta[c];
        if (relu) y = fmaxf(y, 0.f);
        h[i] = y;
    }
}

extern "C" void kernel_launch(void* const* d_in, const int* in_sizes, int n_in,
                              void* d_out, int out_size, void* d_ws, size_t ws_size,
                              hipStream_t stream) {
    const float* x    = (const float*)d_in[0];
    const float* ea   = (const float*)d_in[1];
    const int*   eidx = (const int*)d_in[2];
    const float* W1   = (const float*)d_in[3];
    const float* b1   = (const float*)d_in[4];
    const float* W2   = (const float*)d_in[5];
    const float* b2   = (const float*)d_in[6];
    const float* Wf   = (const float*)d_in[7];
    const float* bf   = (const float*)d_in[8];
    const float* Ws   = (const float*)d_in[9];
    const float* bs   = (const float*)d_in[10];
    const float* gamma= (const float*)d_in[11];
    const float* beta = (const float*)d_in[12];
    float* h = (float*)d_out; // [NNODES, 64], doubles as the h buffer

    // workspace layout (floats)
    float* w = (float*)d_ws;
    float* Wcf  = w;              w += 3 * NBR_FEA * HID;   // 7872
    float* Wcs  = w;              w += 3 * NBR_FEA * HID;   // 7872
    float* bcf  = w;              w += 3 * HID;
    float* bcs  = w;              w += 3 * HID;
    float* Ttgt = w;              w += (long)NNODES * 128;  // 25.6 MB
    float* Tsrc = w;              w += (long)NNODES * 128;  // 25.6 MB
    float* agg  = w;              w += (long)NNODES * HID;  // 12.8 MB
    float* stats= w;              w += 2 * HID;

    combine_weights<<<6, 256, 0, stream>>>(W2, b2, Wf, bf, Ws, bs, Wcf, Wcs, bcf, bcs);
    embed_nodes<<<1024, 256, 0, stream>>>(x, W1, b1, h);

    for (int i = 0; i < 3; ++i) {
        node_proj<<<2048, 256, 0, stream>>>(h, Wf, Ws, bcf, bcs, Ttgt, Tsrc, i);
        hipMemsetAsync(agg, 0, (size_t)NNODES * HID * sizeof(float), stream);
        hipMemsetAsync(stats, 0, 2 * HID * sizeof(float), stream);
        edge_kernel<<<2048, 256, 0, stream>>>(ea, eidx, Ttgt, Tsrc,
                                              Wcf + i * NBR_FEA * HID,
                                              Wcs + i * NBR_FEA * HID, agg);
        bn_stats<<<256, 256, 0, stream>>>(h, agg, stats);
        bn_apply<<<12500, 256, 0, stream>>>(h, agg, stats, gamma + i * HID, beta + i * HID,
                                            (i < 2) ? 1 : 0);
    }
}

// Round 2
// 1596.723 us; speedup vs baseline: 1.2257x; 1.2257x over previous
//
#include <hip/hip_runtime.h>
#include <cmath>

#define NNODES 50000
#define NEDGES 800000
#define ORIG_FEA 92
#define NBR_FEA 41
#define HID 64
#define BN_EPS 1e-5f

typedef __attribute__((ext_vector_type(8))) short short8;
typedef __attribute__((ext_vector_type(4))) float f32x4;
typedef unsigned short ushort;
typedef unsigned int uint;

static __device__ __forceinline__ ushort f2bf(float f) {
    uint u = __float_as_uint(f);
    uint r = u + 0x7fffu + ((u >> 16) & 1u);   // round-to-nearest-even
    return (ushort)(r >> 16);
}

// ---------------------------------------------------------------------------
// Fold embedding2 into per-layer edge weights:
//   Wcf[i] = W2 @ Wf[i][128:192,:]   (41x64), bcf[i] = bf[i] + b2 @ Wf[i][128:192,:]
//   Wcs[i] = W2 @ Ws[i][128:192,:]   (41x64), bcs[i] = bs[i] + b2 @ Ws[i][128:192,:]
// grid = 6 blocks: (layer, f/s)
// ---------------------------------------------------------------------------
__global__ void combine_weights(const float* __restrict__ W2, const float* __restrict__ b2,
                                const float* __restrict__ Wf, const float* __restrict__ bf,
                                const float* __restrict__ Ws, const float* __restrict__ bs,
                                float* __restrict__ Wcf, float* __restrict__ Wcs,
                                float* __restrict__ bcf, float* __restrict__ bcs) {
    int layer = blockIdx.x >> 1;
    int is_s = blockIdx.x & 1;
    const float* Wbig = (is_s ? Ws : Wf) + layer * 192 * HID + 128 * HID; // [64,64] e-part
    const float* bvec = (is_s ? bs : bf) + layer * HID;
    float* Wc = (is_s ? Wcs : Wcf) + layer * NBR_FEA * HID;
    float* bc = (is_s ? bcs : bcf) + layer * HID;

    for (int idx = threadIdx.x; idx < NBR_FEA * HID; idx += blockDim.x) {
        int r = idx / HID, c = idx % HID;
        float acc = 0.f;
        for (int k = 0; k < HID; ++k) acc += W2[r * HID + k] * Wbig[k * HID + c];
        Wc[idx] = acc;
    }
    for (int c = threadIdx.x; c < HID; c += blockDim.x) {
        float acc = bvec[c];
        for (int k = 0; k < HID; ++k) acc += b2[k] * Wbig[k * HID + c];
        bc[c] = acc;
    }
}

// ---------------------------------------------------------------------------
// Pack Wcf/Wcs (fp32 [3][41][64]) into bf16 MFMA B-fragment order:
// WcPack[layer][t(8)][ck(2)][lane(64)][j(8)], k = ck*32 + (lane>>4)*8 + j,
// col = (t&3)*16 + (lane&15); t<4 -> Wcf, t>=4 -> Wcs. k>=41 zero-padded.
// ---------------------------------------------------------------------------
__global__ void pack_edge_weights(const float* __restrict__ Wcf, const float* __restrict__ Wcs,
                                  ushort* __restrict__ WcPack) {
    int idx = blockIdx.x * blockDim.x + threadIdx.x;
    if (idx >= 3 * 8 * 2 * 512) return;
    int j = idx & 7;
    int lane = (idx >> 3) & 63;
    int ck = (idx >> 9) & 1;
    int t = (idx >> 10) & 7;
    int layer = idx >> 13;
    int k = ck * 32 + ((lane >> 4) * 8) + j;
    int col = (t & 3) * 16 + (lane & 15);
    const float* W = ((t < 4) ? Wcf : Wcs) + layer * NBR_FEA * HID;
    float v = (k < NBR_FEA) ? W[k * HID + col] : 0.f;
    WcPack[idx] = f2bf(v);
}

// ---------------------------------------------------------------------------
// ea fp32 [E,41] -> bf16 [E,64] zero-padded. Each thread writes 2 bf16 (4 B).
// ---------------------------------------------------------------------------
__global__ void convert_ea(const float* __restrict__ ea, ushort* __restrict__ eab) {
    long total = (long)NEDGES * 32;
    for (long idx = (long)blockIdx.x * blockDim.x + threadIdx.x; idx < total;
         idx += (long)gridDim.x * blockDim.x) {
        long e = idx >> 5;
        int kk = (int)(idx & 31) * 2;
        float v0 = (kk < NBR_FEA) ? ea[e * NBR_FEA + kk] : 0.f;
        float v1 = (kk + 1 < NBR_FEA) ? ea[e * NBR_FEA + kk + 1] : 0.f;
        uint u0 = f2bf(v0), u1 = f2bf(v1);
        ((uint*)eab)[idx] = (u1 << 16) | u0;
    }
}

// ---------------------------------------------------------------------------
// h = x @ W1 + b1 : one wave per node, lane = output channel
// ---------------------------------------------------------------------------
__global__ void embed_nodes(const float* __restrict__ x, const float* __restrict__ W1,
                            const float* __restrict__ b1, float* __restrict__ h) {
    int lane = threadIdx.x & 63;
    int wid = (blockIdx.x * blockDim.x + threadIdx.x) >> 6;
    int nw = (gridDim.x * blockDim.x) >> 6;
    for (int n = wid; n < NNODES; n += nw) {
        float acc = b1[lane];
        const float* xr = x + (long)n * ORIG_FEA;
        for (int k = 0; k < ORIG_FEA; ++k) acc = fmaf(xr[k], W1[k * HID + lane], acc);
        h[n * HID + lane] = acc;
    }
}

// ---------------------------------------------------------------------------
// Node projections for layer i:
//   Ttgt[n][0:64]   = h@Wf[0:64]   + bcf    Ttgt[n][64:128] = h@Ws[0:64]   + bcs
//   Tsrc[n][0:64]   = h@Wf[64:128]          Tsrc[n][64:128] = h@Ws[64:128]
// ---------------------------------------------------------------------------
__global__ void node_proj(const float* __restrict__ h,
                          const float* __restrict__ Wf, const float* __restrict__ Ws,
                          const float* __restrict__ bcf, const float* __restrict__ bcs,
                          float* __restrict__ Ttgt, float* __restrict__ Tsrc, int layer) {
    __shared__ float Wl[4][HID][HID]; // 64 KB
    int p = threadIdx.x >> 6;
    int c = threadIdx.x & 63;
    const float* Wsrc = ((p == 0) || (p == 2)) ? Wf : Ws;
    int row0 = (p < 2) ? 0 : 64;
    const float* Wbase = Wsrc + layer * 192 * HID + row0 * HID;
    for (int k = 0; k < HID; ++k) Wl[p][k][c] = Wbase[k * HID + c];
    float bias = (p == 0) ? bcf[layer * HID + c] : ((p == 1) ? bcs[layer * HID + c] : 0.f);
    __syncthreads();

    for (int n = blockIdx.x; n < NNODES; n += gridDim.x) {
        const float* hr = h + n * HID;
        float acc = bias;
        #pragma unroll 8
        for (int k = 0; k < HID; ++k) acc = fmaf(hr[k], Wl[p][k][c], acc);
        float* dst = (p == 0) ? (Ttgt + n * 128 + c)
                   : (p == 1) ? (Ttgt + n * 128 + 64 + c)
                   : (p == 2) ? (Tsrc + n * 128 + c)
                              : (Tsrc + n * 128 + 64 + c);
        *dst = acc;
    }
}

// ---------------------------------------------------------------------------
// MFMA edge kernel: one wave per 16 edges (grid-stride over 50000 tiles).
// acc[t] (t=0..7) = ea_tile @ WcPack tile t: 16 edges x 16 channels.
//   t 0..3 -> gate channels t*16+c,  t 4..7 -> softplus channels (t-4)*16+c
// C/D layout: col = lane&15 (=c), row = (lane>>4)*4 + reg  -> edge q*4+reg.
// Epilogue: gather Ttgt/Tsrc (imm-offset loads off per-edge base), activation
// with raw v_exp/v_log/v_rcp, atomicAdd into agg.
// ---------------------------------------------------------------------------
__global__ __launch_bounds__(256) void edge_kernel(
    const ushort* __restrict__ eab, const int* __restrict__ eidx,
    const float* __restrict__ Ttgt, const float* __restrict__ Tsrc,
    const ushort* __restrict__ WcPack, float* __restrict__ agg) {
    int lane = threadIdx.x & 63;
    int q = lane >> 4;
    int c = lane & 15;
    int wid = (blockIdx.x * blockDim.x + threadIdx.x) >> 6;
    int nw = (gridDim.x * blockDim.x) >> 6;

    short8 B[8][2];
    #pragma unroll
    for (int t = 0; t < 8; ++t) {
        #pragma unroll
        for (int ck = 0; ck < 2; ++ck)
            B[t][ck] = *(const short8*)(WcPack + ((t * 2 + ck) * 512 + lane * 8));
    }

    const int ntiles = NEDGES / 16;
    for (int tile = wid; tile < ntiles; tile += nw) {
        int e0 = tile * 16;
        int eL = e0 + c;                 // edge for idx load and A-row (m = c)
        int srcv = eidx[eL];
        int tgtv = eidx[NEDGES + eL];

        const short8* arow = (const short8*)(eab + (long)eL * 64);
        short8 A0 = arow[q];             // k = q*8 .. q*8+7
        short8 A1 = arow[4 + q];         // k = 32 + q*8 ..

        f32x4 acc[8];
        #pragma unroll
        for (int t = 0; t < 8; ++t) {
            acc[t] = __builtin_amdgcn_mfma_f32_16x16x32_bf16(A0, B[t][0],
                        (f32x4){0.f, 0.f, 0.f, 0.f}, 0, 0, 0);
            acc[t] = __builtin_amdgcn_mfma_f32_16x16x32_bf16(A1, B[t][1], acc[t], 0, 0, 0);
        }

        #pragma unroll
        for (int r = 0; r < 4; ++r) {
            int er = q * 4 + r;          // edge row this lane's acc element r holds
            int tg = __shfl(tgtv, er, 64);
            int sv = __shfl(srcv, er, 64);
            const float* pt = Ttgt + (long)tg * 128 + c;
            const float* ps = Tsrc + (long)sv * 128 + c;
            float* pa = agg + (long)tg * 64 + c;
            #pragma unroll
            for (int t = 0; t < 4; ++t) {
                float f = acc[t][r] + pt[t * 16] + ps[t * 16];
                float s = acc[t + 4][r] + pt[64 + t * 16] + ps[64 + t * 16];
                float g = __builtin_amdgcn_rcpf(1.f + __expf(-f));
                float sp = fmaxf(s, 0.f) + __logf(1.f + __expf(-fabsf(s)));
                atomicAdd(pa + t * 16, g * sp);
            }
        }
    }
}

// ---------------------------------------------------------------------------
// BN stats: sum and sumsq per channel of (h + agg). stats pre-zeroed.
// ---------------------------------------------------------------------------
__global__ void bn_stats(const float* __restrict__ h, const float* __restrict__ agg,
                         float* __restrict__ stats) {
    int lane = threadIdx.x & 63;
    int w = threadIdx.x >> 6;
    int gw = (blockIdx.x * blockDim.x + threadIdx.x) >> 6;
    int nw = (gridDim.x * blockDim.x) >> 6;
    float s = 0.f, sq = 0.f;
    for (int n = gw; n < NNODES; n += nw) {
        float v = h[n * HID + lane] + agg[n * HID + lane];
        s += v;
        sq = fmaf(v, v, sq);
    }
    __shared__ float ls[4][64], lq[4][64];
    ls[w][lane] = s; lq[w][lane] = sq;
    __syncthreads();
    if (threadIdx.x < 64) {
        float ts = ls[0][lane] + ls[1][lane] + ls[2][lane] + ls[3][lane];
        float tq = lq[0][lane] + lq[1][lane] + lq[2][lane] + lq[3][lane];
        atomicAdd(&stats[lane], ts);
        atomicAdd(&stats[64 + lane], tq);
    }
}

// ---------------------------------------------------------------------------
// BN apply (+ optional ReLU), in place into h:  h = BN(h + agg)
// ---------------------------------------------------------------------------
__global__ void bn_apply(float* __restrict__ h, const float* __restrict__ agg,
                         const float* __restrict__ stats, const float* __restrict__ gamma,
                         const float* __restrict__ beta, int relu) {
    const float invn = 1.f / (float)NNODES;
    long total = (long)NNODES * HID;
    for (long i = (long)blockIdx.x * blockDim.x + threadIdx.x; i < total;
         i += (long)gridDim.x * blockDim.x) {
        int c = (int)(i & 63);
        float mean = stats[c] * invn;
        float var = stats[64 + c] * invn - mean * mean;
        float rs = rsqrtf(var + BN_EPS);
        float v = h[i] + agg[i];
        float y = (v - mean) * rs * gamma[c] + beta[c];
        if (relu) y = fmaxf(y, 0.f);
        h[i] = y;
    }
}

extern "C" void kernel_launch(void* const* d_in, const int* in_sizes, int n_in,
                              void* d_out, int out_size, void* d_ws, size_t ws_size,
                              hipStream_t stream) {
    const float* x    = (const float*)d_in[0];
    const float* ea   = (const float*)d_in[1];
    const int*   eidx = (const int*)d_in[2];
    const float* W1   = (const float*)d_in[3];
    const float* b1   = (const float*)d_in[4];
    const float* W2   = (const float*)d_in[5];
    const float* b2   = (const float*)d_in[6];
    const float* Wf   = (const float*)d_in[7];
    const float* bf   = (const float*)d_in[8];
    const float* Ws   = (const float*)d_in[9];
    const float* bs   = (const float*)d_in[10];
    const float* gamma= (const float*)d_in[11];
    const float* beta = (const float*)d_in[12];
    float* h = (float*)d_out; // [NNODES, 64]

    // workspace layout
    char* wb = (char*)d_ws;
    ushort* WcPack = (ushort*)wb;          wb += 3 * 8 * 2 * 512 * sizeof(ushort); // 49 KB
    wb = (char*)(((size_t)wb + 255) & ~(size_t)255);
    float* Wcf  = (float*)wb;              wb += 3 * NBR_FEA * HID * sizeof(float);
    float* Wcs  = (float*)wb;              wb += 3 * NBR_FEA * HID * sizeof(float);
    float* bcf  = (float*)wb;              wb += 3 * HID * sizeof(float);
    float* bcs  = (float*)wb;              wb += 3 * HID * sizeof(float);
    float* stats= (float*)wb;              wb += 2 * HID * sizeof(float);
    wb = (char*)(((size_t)wb + 255) & ~(size_t)255);
    float* Ttgt = (float*)wb;              wb += (size_t)NNODES * 128 * sizeof(float); // 25.6 MB
    float* Tsrc = (float*)wb;              wb += (size_t)NNODES * 128 * sizeof(float); // 25.6 MB
    float* agg  = (float*)wb;              wb += (size_t)NNODES * HID * sizeof(float); // 12.8 MB
    ushort* eab = (ushort*)wb;             wb += (size_t)NEDGES * 64 * sizeof(ushort); // 102.4 MB

    combine_weights<<<6, 256, 0, stream>>>(W2, b2, Wf, bf, Ws, bs, Wcf, Wcs, bcf, bcs);
    pack_edge_weights<<<(3 * 8 * 2 * 512 + 255) / 256, 256, 0, stream>>>(Wcf, Wcs, WcPack);
    convert_ea<<<2048, 256, 0, stream>>>(ea, eab);
    embed_nodes<<<1024, 256, 0, stream>>>(x, W1, b1, h);

    for (int i = 0; i < 3; ++i) {
        node_proj<<<2048, 256, 0, stream>>>(h, Wf, Ws, bcf, bcs, Ttgt, Tsrc, i);
        hipMemsetAsync(agg, 0, (size_t)NNODES * HID * sizeof(float), stream);
        hipMemsetAsync(stats, 0, 2 * HID * sizeof(float), stream);
        edge_kernel<<<1024, 256, 0, stream>>>(eab, eidx, Ttgt, Tsrc,
                                              WcPack + i * 8192, agg);
        bn_stats<<<256, 256, 0, stream>>>(h, agg, stats);
        bn_apply<<<12500, 256, 0, stream>>>(h, agg, stats, gamma + i * HID, beta + i * HID,
                                            (i < 2) ? 1 : 0);
    }
}

// Round 3
// 1123.779 us; speedup vs baseline: 1.7415x; 1.4209x over previous
//
#include <hip/hip_runtime.h>
#include <cmath>

#define NNODES 50000
#define NEDGES 800000
#define ORIG_FEA 92
#define NBR_FEA 41
#define HID 64
#define BN_EPS 1e-5f

typedef __attribute__((ext_vector_type(8))) short short8;
typedef __attribute__((ext_vector_type(4))) float f32x4;
typedef unsigned short ushort;
typedef unsigned int uint;

static __device__ __forceinline__ ushort f2bf(float f) {
    uint u = __float_as_uint(f);
    uint r = u + 0x7fffu + ((u >> 16) & 1u);   // round-to-nearest-even
    return (ushort)(r >> 16);
}

// ---------------------------------------------------------------------------
// Fold embedding2 into per-layer edge weights:
//   Wcf[i] = W2 @ Wf[i][128:192,:]   (41x64), bcf[i] = bf[i] + b2 @ Wf[i][128:192,:]
//   Wcs[i] = W2 @ Ws[i][128:192,:]   (41x64), bcs[i] = bs[i] + b2 @ Ws[i][128:192,:]
// ---------------------------------------------------------------------------
__global__ void combine_weights(const float* __restrict__ W2, const float* __restrict__ b2,
                                const float* __restrict__ Wf, const float* __restrict__ bf,
                                const float* __restrict__ Ws, const float* __restrict__ bs,
                                float* __restrict__ Wcf, float* __restrict__ Wcs,
                                float* __restrict__ bcf, float* __restrict__ bcs) {
    int layer = blockIdx.x >> 1;
    int is_s = blockIdx.x & 1;
    const float* Wbig = (is_s ? Ws : Wf) + layer * 192 * HID + 128 * HID; // e-part
    const float* bvec = (is_s ? bs : bf) + layer * HID;
    float* Wc = (is_s ? Wcs : Wcf) + layer * NBR_FEA * HID;
    float* bc = (is_s ? bcs : bcf) + layer * HID;

    for (int idx = threadIdx.x; idx < NBR_FEA * HID; idx += blockDim.x) {
        int r = idx / HID, c = idx % HID;
        float acc = 0.f;
        for (int k = 0; k < HID; ++k) acc += W2[r * HID + k] * Wbig[k * HID + c];
        Wc[idx] = acc;
    }
    for (int c = threadIdx.x; c < HID; c += blockDim.x) {
        float acc = bvec[c];
        for (int k = 0; k < HID; ++k) acc += b2[k] * Wbig[k * HID + c];
        bc[c] = acc;
    }
}

// ---------------------------------------------------------------------------
// Pack combined B = [W_src (64 rows) ; Wc (41 rows, pad to 64)] (K=128, N=128)
// into MFMA B-fragment order:
//   Bpack[layer][t(8)][ck(4)][lane(64)][j(8)], k = ck*32 + (lane>>4)*8 + j,
//   col = (t&3)*16 + (lane&15); t<4 -> f-matrix, t>=4 -> s-matrix.
//   k<64 -> Wbig rows 64..128 (src block); k>=64 -> Wc[k-64] (>=41 zero).
// ---------------------------------------------------------------------------
__global__ void pack_B(const float* __restrict__ Wf, const float* __restrict__ Ws,
                       const float* __restrict__ Wcf, const float* __restrict__ Wcs,
                       ushort* __restrict__ Bpack) {
    int idx = blockIdx.x * blockDim.x + threadIdx.x;
    if (idx >= 3 * 8 * 4 * 512) return;
    int j = idx & 7;
    int lane = (idx >> 3) & 63;
    int ck = (idx >> 9) & 3;
    int t = (idx >> 11) & 7;
    int layer = idx >> 14;
    int k = ck * 32 + ((lane >> 4) * 8) + j;
    int col = (t & 3) * 16 + (lane & 15);
    const float* Wbig = ((t < 4) ? Wf : Ws) + layer * 192 * HID;
    const float* Wc = ((t < 4) ? Wcf : Wcs) + layer * NBR_FEA * HID;
    float v;
    if (k < 64) v = Wbig[(64 + k) * HID + col];
    else if (k - 64 < NBR_FEA) v = Wc[(k - 64) * HID + col];
    else v = 0.f;
    Bpack[idx] = f2bf(v);
}

// ---------------------------------------------------------------------------
// CSR build: histogram -> 3-kernel exclusive scan -> scatter
// ---------------------------------------------------------------------------
__global__ void k_hist(const int* __restrict__ eidx, int* __restrict__ deg) {
    int e = blockIdx.x * blockDim.x + threadIdx.x;
    if (e < NEDGES) atomicAdd(&deg[eidx[NEDGES + e]], 1);
}

__global__ void k_blocksum(const int* __restrict__ deg, int* __restrict__ bsum) {
    __shared__ int sh[256];
    int i = blockIdx.x * 256 + threadIdx.x;
    sh[threadIdx.x] = (i < NNODES) ? deg[i] : 0;
    __syncthreads();
    for (int s = 128; s > 0; s >>= 1) {
        if (threadIdx.x < s) sh[threadIdx.x] += sh[threadIdx.x + s];
        __syncthreads();
    }
    if (threadIdx.x == 0) bsum[blockIdx.x] = sh[0];
}

__global__ void k_scanbase(const int* __restrict__ bsum, int* __restrict__ bbase,
                           int* __restrict__ rowptr) {
    __shared__ int sh[256];
    int t = threadIdx.x;
    int v = (t < 196) ? bsum[t] : 0;
    sh[t] = v;
    __syncthreads();
    for (int s = 1; s < 256; s <<= 1) {
        int add = (t >= s) ? sh[t - s] : 0;
        __syncthreads();
        sh[t] += add;
        __syncthreads();
    }
    if (t < 196) bbase[t] = sh[t] - v;   // exclusive
    if (t == 0) rowptr[NNODES] = NEDGES;
}

__global__ void k_writerow(const int* __restrict__ deg, const int* __restrict__ bbase,
                           int* __restrict__ rowptr, int* __restrict__ cursor) {
    __shared__ int sh[256];
    int t = threadIdx.x;
    int i = blockIdx.x * 256 + t;
    int v = (i < NNODES) ? deg[i] : 0;
    sh[t] = v;
    __syncthreads();
    for (int s = 1; s < 256; s <<= 1) {
        int add = (t >= s) ? sh[t - s] : 0;
        __syncthreads();
        sh[t] += add;
        __syncthreads();
    }
    if (i < NNODES) {
        int e = bbase[blockIdx.x] + sh[t] - v;
        rowptr[i] = e;
        cursor[i] = e;
    }
}

__global__ void k_scatterA(const int* __restrict__ eidx, int* __restrict__ cursor,
                           int* __restrict__ eperm, int* __restrict__ srcs) {
    int e = blockIdx.x * blockDim.x + threadIdx.x;
    if (e < NEDGES) {
        int tgt = eidx[NEDGES + e];
        int pos = atomicAdd(&cursor[tgt], 1);
        eperm[e] = pos;
        srcs[pos] = eidx[e];
    }
}

// fp32 ea [E,41] -> bf16, zero-padded [*,64], permuted to sorted position.
__global__ void k_scatterB(const float* __restrict__ ea, const int* __restrict__ eperm,
                           ushort* __restrict__ eab_s) {
    long idx = (long)blockIdx.x * blockDim.x + threadIdx.x;
    if (idx >= (long)NEDGES * 8) return;
    int e = (int)(idx >> 3);
    int j = (int)(idx & 7);
    int pos = eperm[e];
    uint4 o;
    uint w[4];
    #pragma unroll
    for (int m = 0; m < 4; ++m) {
        int k0 = j * 8 + m * 2, k1 = k0 + 1;
        uint u0 = (k0 < NBR_FEA) ? (uint)f2bf(ea[(long)e * NBR_FEA + k0]) : 0u;
        uint u1 = (k1 < NBR_FEA) ? (uint)f2bf(ea[(long)e * NBR_FEA + k1]) : 0u;
        w[m] = u0 | (u1 << 16);
    }
    o.x = w[0]; o.y = w[1]; o.z = w[2]; o.w = w[3];
    *(uint4*)(eab_s + (long)pos * 64 + j * 8) = o;
}

// ---------------------------------------------------------------------------
// h = x @ W1 + b1 (fp32) + bf16 copy for the edge-kernel src gather
// ---------------------------------------------------------------------------
__global__ void embed_nodes(const float* __restrict__ x, const float* __restrict__ W1,
                            const float* __restrict__ b1, float* __restrict__ h,
                            ushort* __restrict__ h_bf) {
    int lane = threadIdx.x & 63;
    int wid = (blockIdx.x * blockDim.x + threadIdx.x) >> 6;
    int nw = (gridDim.x * blockDim.x) >> 6;
    for (int n = wid; n < NNODES; n += nw) {
        float acc = b1[lane];
        const float* xr = x + (long)n * ORIG_FEA;
        for (int k = 0; k < ORIG_FEA; ++k) acc = fmaf(xr[k], W1[k * HID + lane], acc);
        h[n * HID + lane] = acc;
        h_bf[n * HID + lane] = f2bf(acc);
    }
}

// ---------------------------------------------------------------------------
// Target-side projection only (src rides the edge MFMA now):
//   Ttgt[n][0:64] = h@Wf[0:64] + bcf ;  Ttgt[n][64:128] = h@Ws[0:64] + bcs
// 4 waves/block: (fs = p&1 selects f/s, p>>1 selects node n0 / n0+1)
// ---------------------------------------------------------------------------
__global__ void node_proj(const float* __restrict__ h,
                          const float* __restrict__ Wf, const float* __restrict__ Ws,
                          const float* __restrict__ bcf, const float* __restrict__ bcs,
                          float* __restrict__ Ttgt, int layer) {
    __shared__ float Wl[2][HID][HID]; // 32 KB
    int p = threadIdx.x >> 6;
    int c = threadIdx.x & 63;
    int fs = p & 1;
    int half = p >> 1;
    const float* Wbase = (fs ? Ws : Wf) + layer * 192 * HID;  // rows 0..64 = tgt block
    for (int k = half * 32; k < half * 32 + 32; ++k)
        Wl[fs][k][c] = Wbase[k * HID + c];
    float bias = fs ? bcs[layer * HID + c] : bcf[layer * HID + c];
    __syncthreads();

    for (int n0 = blockIdx.x * 2; n0 < NNODES; n0 += gridDim.x * 2) {
        int n = n0 + half;
        if (n < NNODES) {
            const float* hr = h + (long)n * HID;
            float acc = bias;
            #pragma unroll 8
            for (int k = 0; k < HID; ++k) acc = fmaf(hr[k], Wl[fs][k][c], acc);
            Ttgt[(long)n * 128 + fs * 64 + c] = acc;
        }
    }
}

// ---------------------------------------------------------------------------
// Edge kernel, CSR form: ONE WAVE PER TARGET (grid-stride).
// Per 16-edge chunk: A = [h_bf[src] (k 0..63) | eab_sorted (k 64..127)],
// 8 output tiles x 4 K-chunks of mfma_f32_16x16x32_bf16. Epilogue adds the
// per-target Ttgt row, applies sigmoid*softplus, masks padded rows, and
// accumulates in registers. One butterfly + one coalesced 256 B store per
// target. No atomics; agg needs no pre-zeroing (every target written).
// ---------------------------------------------------------------------------
__global__ __launch_bounds__(256, 2) void edge_kernel(
    const ushort* __restrict__ eab_s, const int* __restrict__ srcs,
    const int* __restrict__ rowptr, const ushort* __restrict__ h_bf,
    const float* __restrict__ Ttgt, const ushort* __restrict__ Bpack,
    float* __restrict__ agg) {
    int lane = threadIdx.x & 63;
    int q = lane >> 4;
    int c = lane & 15;
    int wid = (blockIdx.x * blockDim.x + threadIdx.x) >> 6;
    int nw = (gridDim.x * blockDim.x) >> 6;

    short8 B[8][4];
    #pragma unroll
    for (int t = 0; t < 8; ++t)
        #pragma unroll
        for (int ck = 0; ck < 4; ++ck)
            B[t][ck] = *(const short8*)(Bpack + ((t * 4 + ck) * 512 + lane * 8));

    for (int tn = wid; tn < NNODES; tn += nw) {
        int r0 = rowptr[tn], r1 = rowptr[tn + 1];
        int d = r1 - r0;
        float vs0 = 0.f, vs1 = 0.f, vs2 = 0.f, vs3 = 0.f;
        if (d > 0) {
            const float* tp = Ttgt + (long)tn * 128 + c;
            float tf[4], ts[4];
            #pragma unroll
            for (int t = 0; t < 4; ++t) { tf[t] = tp[16 * t]; ts[t] = tp[64 + 16 * t]; }

            for (int cs = 0; cs < d; cs += 16) {
                int ei = r0 + cs + c;
                if (ei > r1 - 1) ei = r1 - 1;          // clamp padded rows
                int sv = srcs[ei];
                const short8* hrow = (const short8*)(h_bf + (long)sv * 64);
                const short8* erow = (const short8*)(eab_s + (long)ei * 64);
                short8 A0 = hrow[q], A1 = hrow[4 + q];
                short8 A2 = erow[q], A3 = erow[4 + q];

                f32x4 accf[4], accs[4];
                #pragma unroll
                for (int t = 0; t < 4; ++t) {
                    f32x4 z = {0.f, 0.f, 0.f, 0.f};
                    accf[t] = __builtin_amdgcn_mfma_f32_16x16x32_bf16(A0, B[t][0], z, 0, 0, 0);
                    accf[t] = __builtin_amdgcn_mfma_f32_16x16x32_bf16(A1, B[t][1], accf[t], 0, 0, 0);
                    accf[t] = __builtin_amdgcn_mfma_f32_16x16x32_bf16(A2, B[t][2], accf[t], 0, 0, 0);
                    accf[t] = __builtin_amdgcn_mfma_f32_16x16x32_bf16(A3, B[t][3], accf[t], 0, 0, 0);
                    accs[t] = __builtin_amdgcn_mfma_f32_16x16x32_bf16(A0, B[t + 4][0], z, 0, 0, 0);
                    accs[t] = __builtin_amdgcn_mfma_f32_16x16x32_bf16(A1, B[t + 4][1], accs[t], 0, 0, 0);
                    accs[t] = __builtin_amdgcn_mfma_f32_16x16x32_bf16(A2, B[t + 4][2], accs[t], 0, 0, 0);
                    accs[t] = __builtin_amdgcn_mfma_f32_16x16x32_bf16(A3, B[t + 4][3], accs[t], 0, 0, 0);
                }

                #pragma unroll
                for (int r = 0; r < 4; ++r) {
                    int er = q * 4 + r;
                    bool valid = (cs + er) < d;
                    #pragma unroll
                    for (int t = 0; t < 4; ++t) {
                        float f = accf[t][r] + tf[t];
                        float s = accs[t][r] + ts[t];
                        float g = __builtin_amdgcn_rcpf(1.f + __expf(-f));
                        float sp = fmaxf(s, 0.f) + __logf(1.f + __expf(-fabsf(s)));
                        float msg = valid ? g * sp : 0.f;
                        if (t == 0) vs0 += msg;
                        else if (t == 1) vs1 += msg;
                        else if (t == 2) vs2 += msg;
                        else vs3 += msg;
                    }
                }
            }
            vs0 += __shfl_xor(vs0, 16, 64); vs0 += __shfl_xor(vs0, 32, 64);
            vs1 += __shfl_xor(vs1, 16, 64); vs1 += __shfl_xor(vs1, 32, 64);
            vs2 += __shfl_xor(vs2, 16, 64); vs2 += __shfl_xor(vs2, 32, 64);
            vs3 += __shfl_xor(vs3, 16, 64); vs3 += __shfl_xor(vs3, 32, 64);
        }
        float out = (q == 0) ? vs0 : (q == 1) ? vs1 : (q == 2) ? vs2 : vs3;
        agg[(long)tn * 64 + lane] = out;   // channel = q*16 + c = lane
    }
}

// ---------------------------------------------------------------------------
// BN stats: sum and sumsq per channel of (h + agg). stats pre-zeroed.
// ---------------------------------------------------------------------------
__global__ void bn_stats(const float* __restrict__ h, const float* __restrict__ agg,
                         float* __restrict__ stats) {
    int lane = threadIdx.x & 63;
    int w = threadIdx.x >> 6;
    int gw = (blockIdx.x * blockDim.x + threadIdx.x) >> 6;
    int nw = (gridDim.x * blockDim.x) >> 6;
    float s = 0.f, sq = 0.f;
    for (int n = gw; n < NNODES; n += nw) {
        float v = h[n * HID + lane] + agg[n * HID + lane];
        s += v;
        sq = fmaf(v, v, sq);
    }
    __shared__ float ls[4][64], lq[4][64];
    ls[w][lane] = s; lq[w][lane] = sq;
    __syncthreads();
    if (threadIdx.x < 64) {
        float ts = ls[0][lane] + ls[1][lane] + ls[2][lane] + ls[3][lane];
        float tq = lq[0][lane] + lq[1][lane] + lq[2][lane] + lq[3][lane];
        atomicAdd(&stats[lane], ts);
        atomicAdd(&stats[64 + lane], tq);
    }
}

// ---------------------------------------------------------------------------
// BN apply (+ optional ReLU), in place into h, plus bf16 copy for next layer
// ---------------------------------------------------------------------------
__global__ void bn_apply(float* __restrict__ h, const float* __restrict__ agg,
                         const float* __restrict__ stats, const float* __restrict__ gamma,
                         const float* __restrict__ beta, ushort* __restrict__ h_bf,
                         int relu) {
    const float invn = 1.f / (float)NNODES;
    long total = (long)NNODES * HID;
    for (long i = (long)blockIdx.x * blockDim.x + threadIdx.x; i < total;
         i += (long)gridDim.x * blockDim.x) {
        int c = (int)(i & 63);
        float mean = stats[c] * invn;
        float var = stats[64 + c] * invn - mean * mean;
        float rs = rsqrtf(var + BN_EPS);
        float v = h[i] + agg[i];
        float y = (v - mean) * rs * gamma[c] + beta[c];
        if (relu) y = fmaxf(y, 0.f);
        h[i] = y;
        h_bf[i] = f2bf(y);
    }
}

extern "C" void kernel_launch(void* const* d_in, const int* in_sizes, int n_in,
                              void* d_out, int out_size, void* d_ws, size_t ws_size,
                              hipStream_t stream) {
    const float* x    = (const float*)d_in[0];
    const float* ea   = (const float*)d_in[1];
    const int*   eidx = (const int*)d_in[2];
    const float* W1   = (const float*)d_in[3];
    const float* b1   = (const float*)d_in[4];
    const float* W2   = (const float*)d_in[5];
    const float* b2   = (const float*)d_in[6];
    const float* Wf   = (const float*)d_in[7];
    const float* bf   = (const float*)d_in[8];
    const float* Ws   = (const float*)d_in[9];
    const float* bs   = (const float*)d_in[10];
    const float* gamma= (const float*)d_in[11];
    const float* beta = (const float*)d_in[12];
    float* h = (float*)d_out; // [NNODES, 64]

    // workspace layout (256 B aligned sections)
    char* wb = (char*)d_ws;
    auto align = [&]() { wb = (char*)(((size_t)wb + 255) & ~(size_t)255); };
    ushort* Bpack = (ushort*)wb;  wb += 3 * 8 * 4 * 512 * sizeof(ushort); align(); // 96 KB
    float* Wcf   = (float*)wb;    wb += 3 * NBR_FEA * HID * sizeof(float);
    float* Wcs   = (float*)wb;    wb += 3 * NBR_FEA * HID * sizeof(float);
    float* bcf   = (float*)wb;    wb += 3 * HID * sizeof(float);
    float* bcs   = (float*)wb;    wb += 3 * HID * sizeof(float);
    float* stats = (float*)wb;    wb += 2 * HID * sizeof(float); align();
    int* deg     = (int*)wb;      wb += NNODES * sizeof(int);
    int* rowptr  = (int*)wb;      wb += (NNODES + 1) * sizeof(int);
    int* cursor  = (int*)wb;      wb += NNODES * sizeof(int);
    int* bsum    = (int*)wb;      wb += 256 * sizeof(int);
    int* bbase   = (int*)wb;      wb += 256 * sizeof(int); align();
    int* eperm   = (int*)wb;      wb += NEDGES * sizeof(int);          // 3.2 MB
    int* srcs    = (int*)wb;      wb += NEDGES * sizeof(int);          // 3.2 MB
    align();
    float* Ttgt  = (float*)wb;    wb += (size_t)NNODES * 128 * sizeof(float); // 25.6 MB
    float* agg   = (float*)wb;    wb += (size_t)NNODES * HID * sizeof(float); // 12.8 MB
    ushort* h_bf = (ushort*)wb;   wb += (size_t)NNODES * HID * sizeof(ushort); // 6.4 MB
    ushort* eab_s= (ushort*)wb;   wb += (size_t)NEDGES * 64 * sizeof(ushort);  // 102.4 MB

    // --- setup: weights, CSR sort, embed ---
    combine_weights<<<6, 256, 0, stream>>>(W2, b2, Wf, bf, Ws, bs, Wcf, Wcs, bcf, bcs);
    pack_B<<<(3 * 8 * 4 * 512 + 255) / 256, 256, 0, stream>>>(Wf, Ws, Wcf, Wcs, Bpack);

    hipMemsetAsync(deg, 0, NNODES * sizeof(int), stream);
    k_hist<<<(NEDGES + 255) / 256, 256, 0, stream>>>(eidx, deg);
    k_blocksum<<<196, 256, 0, stream>>>(deg, bsum);
    k_scanbase<<<1, 256, 0, stream>>>(bsum, bbase, rowptr);
    k_writerow<<<196, 256, 0, stream>>>(deg, bbase, rowptr, cursor);
    k_scatterA<<<(NEDGES + 255) / 256, 256, 0, stream>>>(eidx, cursor, eperm, srcs);
    k_scatterB<<<(NEDGES * 8 + 255) / 256, 256, 0, stream>>>(ea, eperm, eab_s);

    embed_nodes<<<1024, 256, 0, stream>>>(x, W1, b1, h, h_bf);

    for (int i = 0; i < 3; ++i) {
        node_proj<<<4096, 256, 0, stream>>>(h, Wf, Ws, bcf, bcs, Ttgt, i);
        hipMemsetAsync(stats, 0, 2 * HID * sizeof(float), stream);
        edge_kernel<<<2048, 256, 0, stream>>>(eab_s, srcs, rowptr, h_bf, Ttgt,
                                              Bpack + i * 16384, agg);
        bn_stats<<<1024, 256, 0, stream>>>(h, agg, stats);
        bn_apply<<<12500, 256, 0, stream>>>(h, agg, stats, gamma + i * HID, beta + i * HID,
                                            h_bf, (i < 2) ? 1 : 0);
    }
}